// Round 1
// baseline (1892.053 us; speedup 1.0000x reference)
//
#include <hip/hip_runtime.h>
#include <hip/hip_bf16.h>
#include <math.h>

#define T_TOK 4096
#define H_DIM 2048
#define D_DIM 2048
#define TWO_D 4096
#define E_NUM 16
#define NPAIR (T_TOK * 4)

typedef __attribute__((ext_vector_type(8))) short v8s;
typedef __attribute__((ext_vector_type(4))) float v4f;

__device__ __forceinline__ ushort f2bf(float f) {
    union { float f; unsigned u; } v; v.f = f;
    unsigned u = v.u + 0x7fffu + ((v.u >> 16) & 1u);
    return (ushort)(u >> 16);
}
__device__ __forceinline__ float bf2f(ushort b) {
    union { unsigned u; float f; } v; v.u = ((unsigned)b) << 16;
    return v.f;
}

// ---------------- convert x to bf16 ----------------
__global__ void k_convert_x(const float* __restrict__ x, ushort* __restrict__ xb) {
    size_t i = ((size_t)blockIdx.x * 256 + threadIdx.x) * 4;
    float4 v = *(const float4*)(x + i);
    ushort4 o = make_ushort4(f2bf(v.x), f2bf(v.y), f2bf(v.z), f2bf(v.w));
    *(ushort4*)(xb + i) = o;
}

// ---------------- router logits (fp32) ----------------
__global__ void k_router(const float* __restrict__ x, const float* __restrict__ rw,
                         const float* __restrict__ rb, float* __restrict__ logits) {
    int t = blockIdx.x;
    int e = threadIdx.x >> 4;
    int j = threadIdx.x & 15;
    const float* xr = x + (size_t)t * H_DIM;
    const float* wr = rw + (size_t)e * H_DIM;
    float s = 0.f;
    #pragma unroll 8
    for (int h = j; h < H_DIM; h += 16) s += xr[h] * wr[h];
    #pragma unroll
    for (int d = 8; d >= 1; d >>= 1) s += __shfl_down(s, d, 16);
    if (j == 0) logits[t * E_NUM + e] = s + rb[e];
}

// ---------------- top-k + softmax ----------------
__global__ void k_topk(const float* __restrict__ logits, float* __restrict__ scores_out,
                       int* __restrict__ tk_e, float* __restrict__ tk_w,
                       int* __restrict__ counts) {
    int t = blockIdx.x * 256 + threadIdx.x;
    if (t >= T_TOK) return;
    float lg[E_NUM];
    #pragma unroll
    for (int e = 0; e < E_NUM; e++) lg[e] = logits[t * E_NUM + e];
    int sel[4]; float sv[4];
    unsigned used = 0;
    #pragma unroll
    for (int k = 0; k < 4; k++) {
        float best = -INFINITY; int bi = 0;
        #pragma unroll
        for (int e = 0; e < E_NUM; e++) {
            if (!((used >> e) & 1) && lg[e] > best) { best = lg[e]; bi = e; }
        }
        used |= 1u << bi; sel[k] = bi; sv[k] = best;
    }
    float m = sv[0];
    float ex[4]; float sum = 0.f;
    #pragma unroll
    for (int k = 0; k < 4; k++) { ex[k] = __expf(sv[k] - m); sum += ex[k]; }
    float inv = 1.f / sum;
    #pragma unroll
    for (int k = 0; k < 4; k++) {
        float w = ex[k] * inv;
        scores_out[t * 4 + k] = w * 0.25f;
        tk_e[t * 4 + k] = sel[k];
        tk_w[t * 4 + k] = w;
        atomicAdd(&counts[sel[k]], 1);
    }
}

// ---------------- scan counts -> offsets ----------------
__global__ void k_scan(const int* __restrict__ counts, int* __restrict__ offsets) {
    if (threadIdx.x == 0) {
        int s = 0;
        for (int e = 0; e < E_NUM; e++) { offsets[e] = s; s += counts[e]; }
        offsets[E_NUM] = s;
    }
}

// ---------------- scatter pairs into expert-grouped order ----------------
__global__ void k_scatter(const int* __restrict__ tk_e, const int* __restrict__ offsets,
                          int* __restrict__ fill, int* __restrict__ pair_token,
                          int* __restrict__ slot_of) {
    int i = blockIdx.x * 256 + threadIdx.x;
    if (i >= NPAIR) return;
    int e = tk_e[i];
    int pos = offsets[e] + atomicAdd(&fill[e], 1);
    pair_token[pos] = i >> 2;
    slot_of[i] = pos;
}

// ---------------- GEMM tile params ----------------
#define BM 128
#define BN 128
#define BK 64
#define LDT 72  // bf16 elems per LDS row (64 + 8 pad) = 144B

// ---------------- GEMM1: gathered x @ Wgu + bias -> gate_up (bf16) ----------------
__global__ __launch_bounds__(256) void k_gemm1(
    const ushort* __restrict__ xb, const float* __restrict__ Wgu,
    const float* __restrict__ bgu, const int* __restrict__ offsets,
    const int* __restrict__ pair_token, ushort* __restrict__ gu)
{
    __shared__ ushort As[BM * LDT];
    __shared__ ushort Bs[BN * LDT];
    __shared__ int rowtok[BM];

    const int e = blockIdx.z;
    const int off = offsets[e];
    const int cnt = offsets[e + 1] - off;
    const int m0 = blockIdx.y * BM;
    if (m0 >= cnt) return;
    const int n0 = blockIdx.x * BN;
    const int tid = threadIdx.x;

    if (tid < BM) {
        int r = m0 + tid; if (r >= cnt) r = cnt - 1;
        rowtok[tid] = pair_token[off + r];
    }

    const float* W = Wgu + (size_t)e * H_DIM * TWO_D + n0;

    v4f acc[4][4];
    #pragma unroll
    for (int i = 0; i < 4; i++)
        #pragma unroll
        for (int j = 0; j < 4; j++) acc[i][j] = (v4f){0.f, 0.f, 0.f, 0.f};

    const int lane = tid & 63;
    const int wm = ((tid >> 6) & 1) * 64;
    const int wn = (tid >> 7) * 64;
    const int lm = lane & 15;
    const int kg = lane >> 4;

    for (int kb = 0; kb < H_DIM; kb += BK) {
        __syncthreads();
        // stage A (gathered rows), 16B per chunk
        #pragma unroll
        for (int i = 0; i < 4; i++) {
            int c = tid + 256 * i;
            int row = c >> 3, cq = c & 7;
            const ushort* src = xb + (size_t)rowtok[row] * H_DIM + kb + cq * 8;
            *(uint4*)&As[row * LDT + cq * 8] = *(const uint4*)src;
        }
        // stage B with fp32->bf16 convert + transpose to [n][k]
        #pragma unroll
        for (int i = 0; i < 2; i++) {
            int blk = tid + 256 * i;
            int kb4 = blk >> 5, nb4 = blk & 31;
            const float* wp = W + (size_t)(kb + kb4 * 4) * TWO_D + nb4 * 4;
            float4 r0 = *(const float4*)wp;
            float4 r1 = *(const float4*)(wp + TWO_D);
            float4 r2 = *(const float4*)(wp + 2 * TWO_D);
            float4 r3 = *(const float4*)(wp + 3 * TWO_D);
            ushort* bp = &Bs[(nb4 * 4) * LDT + kb4 * 4];
            *(ushort4*)bp             = make_ushort4(f2bf(r0.x), f2bf(r1.x), f2bf(r2.x), f2bf(r3.x));
            *(ushort4*)(bp + LDT)     = make_ushort4(f2bf(r0.y), f2bf(r1.y), f2bf(r2.y), f2bf(r3.y));
            *(ushort4*)(bp + 2 * LDT) = make_ushort4(f2bf(r0.z), f2bf(r1.z), f2bf(r2.z), f2bf(r3.z));
            *(ushort4*)(bp + 3 * LDT) = make_ushort4(f2bf(r0.w), f2bf(r1.w), f2bf(r2.w), f2bf(r3.w));
        }
        __syncthreads();
        #pragma unroll
        for (int ks = 0; ks < 2; ks++) {
            v8s af[4], bfr[4];
            #pragma unroll
            for (int mi = 0; mi < 4; mi++)
                af[mi] = *(const v8s*)&As[(wm + mi * 16 + lm) * LDT + ks * 32 + kg * 8];
            #pragma unroll
            for (int ni = 0; ni < 4; ni++)
                bfr[ni] = *(const v8s*)&Bs[(wn + ni * 16 + lm) * LDT + ks * 32 + kg * 8];
            #pragma unroll
            for (int mi = 0; mi < 4; mi++)
                #pragma unroll
                for (int ni = 0; ni < 4; ni++)
                    acc[mi][ni] = __builtin_amdgcn_mfma_f32_16x16x32_bf16(af[mi], bfr[ni], acc[mi][ni], 0, 0, 0);
        }
    }

    const float* bias = bgu + (size_t)e * TWO_D + n0;
    #pragma unroll
    for (int mi = 0; mi < 4; mi++) {
        int rbase = wm + mi * 16 + kg * 4;
        #pragma unroll
        for (int ni = 0; ni < 4; ni++) {
            int nl = wn + ni * 16 + lm;
            float bv = bias[nl];
            #pragma unroll
            for (int v = 0; v < 4; v++) {
                int r = rbase + v;
                if (m0 + r < cnt)
                    gu[(size_t)(off + m0 + r) * TWO_D + n0 + nl] = f2bf(acc[mi][ni][v] + bv);
            }
        }
    }
}

// ---------------- activation: clamp + GLU -> gated (bf16) ----------------
__global__ void k_act(const ushort* __restrict__ gu, ushort* __restrict__ gated) {
    int i = blockIdx.x * 256 + threadIdx.x;
    int pr = i >> 9;
    int q = (i & 511) * 4;
    const ushort* grow = gu + (size_t)pr * TWO_D;
    ushort4 g4 = *(const ushort4*)(grow + q);
    ushort4 u4 = *(const ushort4*)(grow + D_DIM + q);
    float g[4] = { bf2f(g4.x), bf2f(g4.y), bf2f(g4.z), bf2f(g4.w) };
    float u[4] = { bf2f(u4.x), bf2f(u4.y), bf2f(u4.z), bf2f(u4.w) };
    ushort o[4];
    #pragma unroll
    for (int j = 0; j < 4; j++) {
        float gate = fminf(g[j], 7.f);
        float up = fminf(fmaxf(u[j], -7.f), 7.f);
        float glu = gate / (1.f + __expf(-1.702f * gate));
        o[j] = f2bf((up + 1.f) * glu);
    }
    *(ushort4*)(gated + (size_t)pr * D_DIM + q) = make_ushort4(o[0], o[1], o[2], o[3]);
}

// ---------------- GEMM2: gated @ Wd + bias -> pairout (bf16) ----------------
__global__ __launch_bounds__(256) void k_gemm2(
    const ushort* __restrict__ gated, const float* __restrict__ Wd,
    const float* __restrict__ bd, const int* __restrict__ offsets,
    ushort* __restrict__ po)
{
    __shared__ ushort As[BM * LDT];
    __shared__ ushort Bs[BN * LDT];

    const int e = blockIdx.z;
    const int off = offsets[e];
    const int cnt = offsets[e + 1] - off;
    const int m0 = blockIdx.y * BM;
    if (m0 >= cnt) return;
    const int n0 = blockIdx.x * BN;
    const int tid = threadIdx.x;

    const float* W = Wd + (size_t)e * D_DIM * H_DIM + n0;

    v4f acc[4][4];
    #pragma unroll
    for (int i = 0; i < 4; i++)
        #pragma unroll
        for (int j = 0; j < 4; j++) acc[i][j] = (v4f){0.f, 0.f, 0.f, 0.f};

    const int lane = tid & 63;
    const int wm = ((tid >> 6) & 1) * 64;
    const int wn = (tid >> 7) * 64;
    const int lm = lane & 15;
    const int kg = lane >> 4;

    for (int kb = 0; kb < D_DIM; kb += BK) {
        __syncthreads();
        #pragma unroll
        for (int i = 0; i < 4; i++) {
            int c = tid + 256 * i;
            int row = c >> 3, cq = c & 7;
            int gr = m0 + row; if (gr >= cnt) gr = cnt - 1;
            const ushort* src = gated + (size_t)(off + gr) * D_DIM + kb + cq * 8;
            *(uint4*)&As[row * LDT + cq * 8] = *(const uint4*)src;
        }
        #pragma unroll
        for (int i = 0; i < 2; i++) {
            int blk = tid + 256 * i;
            int kb4 = blk >> 5, nb4 = blk & 31;
            const float* wp = W + (size_t)(kb + kb4 * 4) * H_DIM + nb4 * 4;
            float4 r0 = *(const float4*)wp;
            float4 r1 = *(const float4*)(wp + H_DIM);
            float4 r2 = *(const float4*)(wp + 2 * H_DIM);
            float4 r3 = *(const float4*)(wp + 3 * H_DIM);
            ushort* bp = &Bs[(nb4 * 4) * LDT + kb4 * 4];
            *(ushort4*)bp             = make_ushort4(f2bf(r0.x), f2bf(r1.x), f2bf(r2.x), f2bf(r3.x));
            *(ushort4*)(bp + LDT)     = make_ushort4(f2bf(r0.y), f2bf(r1.y), f2bf(r2.y), f2bf(r3.y));
            *(ushort4*)(bp + 2 * LDT) = make_ushort4(f2bf(r0.z), f2bf(r1.z), f2bf(r2.z), f2bf(r3.z));
            *(ushort4*)(bp + 3 * LDT) = make_ushort4(f2bf(r0.w), f2bf(r1.w), f2bf(r2.w), f2bf(r3.w));
        }
        __syncthreads();
        #pragma unroll
        for (int ks = 0; ks < 2; ks++) {
            v8s af[4], bfr[4];
            #pragma unroll
            for (int mi = 0; mi < 4; mi++)
                af[mi] = *(const v8s*)&As[(wm + mi * 16 + lm) * LDT + ks * 32 + kg * 8];
            #pragma unroll
            for (int ni = 0; ni < 4; ni++)
                bfr[ni] = *(const v8s*)&Bs[(wn + ni * 16 + lm) * LDT + ks * 32 + kg * 8];
            #pragma unroll
            for (int mi = 0; mi < 4; mi++)
                #pragma unroll
                for (int ni = 0; ni < 4; ni++)
                    acc[mi][ni] = __builtin_amdgcn_mfma_f32_16x16x32_bf16(af[mi], bfr[ni], acc[mi][ni], 0, 0, 0);
        }
    }

    const float* bias = bd + (size_t)e * H_DIM + n0;
    #pragma unroll
    for (int mi = 0; mi < 4; mi++) {
        int rbase = wm + mi * 16 + kg * 4;
        #pragma unroll
        for (int ni = 0; ni < 4; ni++) {
            int nl = wn + ni * 16 + lm;
            float bv = bias[nl];
            #pragma unroll
            for (int v = 0; v < 4; v++) {
                int r = rbase + v;
                if (m0 + r < cnt)
                    po[(size_t)(off + m0 + r) * H_DIM + n0 + nl] = f2bf(acc[mi][ni][v] + bv);
            }
        }
    }
}

// ---------------- combine: y[t] = sum_k w_k * pairout[slot(t,k)] ----------------
__global__ void k_combine(const ushort* __restrict__ po, const int* __restrict__ slot_of,
                          const float* __restrict__ tk_w, float* __restrict__ y) {
    const int t = blockIdx.x;
    int s[4]; float w[4];
    #pragma unroll
    for (int k = 0; k < 4; k++) { s[k] = slot_of[t * 4 + k]; w[k] = tk_w[t * 4 + k]; }
    const int h = threadIdx.x * 8;
    float acc[8];
    #pragma unroll
    for (int j = 0; j < 8; j++) acc[j] = 0.f;
    #pragma unroll
    for (int k = 0; k < 4; k++) {
        const ushort* row = po + (size_t)s[k] * H_DIM + h;
        ushort4 a = *(const ushort4*)row;
        ushort4 b = *(const ushort4*)(row + 4);
        acc[0] += w[k] * bf2f(a.x); acc[1] += w[k] * bf2f(a.y);
        acc[2] += w[k] * bf2f(a.z); acc[3] += w[k] * bf2f(a.w);
        acc[4] += w[k] * bf2f(b.x); acc[5] += w[k] * bf2f(b.y);
        acc[6] += w[k] * bf2f(b.z); acc[7] += w[k] * bf2f(b.w);
    }
    float* yp = y + (size_t)t * H_DIM + h;
    *(float4*)yp = make_float4(acc[0], acc[1], acc[2], acc[3]);
    *(float4*)(yp + 4) = make_float4(acc[4], acc[5], acc[6], acc[7]);
}

extern "C" void kernel_launch(void* const* d_in, const int* in_sizes, int n_in,
                              void* d_out, int out_size, void* d_ws, size_t ws_size,
                              hipStream_t stream) {
    const float* x   = (const float*)d_in[0];
    const float* rw  = (const float*)d_in[1];
    const float* rb  = (const float*)d_in[2];
    const float* wgu = (const float*)d_in[3];
    const float* bgu = (const float*)d_in[4];
    const float* wd  = (const float*)d_in[5];
    const float* bd  = (const float*)d_in[6];
    float* y = (float*)d_out;
    float* scores = y + (size_t)T_TOK * H_DIM;

    char* p = (char*)d_ws;
    auto alloc = [&](size_t bytes) { char* r = p; p += (bytes + 255) & ~(size_t)255; return r; };
    ushort* xb         = (ushort*)alloc((size_t)T_TOK * H_DIM * 2);
    float*  logits     = (float*) alloc((size_t)T_TOK * E_NUM * 4);
    int*    tk_e       = (int*)   alloc(NPAIR * 4);
    float*  tk_w       = (float*) alloc(NPAIR * 4);
    int*    slot_of    = (int*)   alloc(NPAIR * 4);
    int*    pair_token = (int*)   alloc(NPAIR * 4);
    int*    cnt_fill   = (int*)   alloc(512);   // counts[16] @ +0, fill[16] @ +256
    int*    offsets    = (int*)   alloc(128);   // [17]
    ushort* gu         = (ushort*)alloc((size_t)NPAIR * TWO_D * 2);
    ushort* gated      = (ushort*)alloc((size_t)NPAIR * D_DIM * 2);
    ushort* pairout    = gu;  // alias: gu dead after k_act
    int* counts = cnt_fill;
    int* fill   = cnt_fill + 64;

    hipMemsetAsync(cnt_fill, 0, 512, stream);
    k_convert_x<<<(T_TOK * H_DIM) / (256 * 4), 256, 0, stream>>>(x, xb);
    k_router<<<T_TOK, 256, 0, stream>>>(x, rw, rb, logits);
    k_topk<<<T_TOK / 256, 256, 0, stream>>>(logits, scores, tk_e, tk_w, counts);
    k_scan<<<1, 64, 0, stream>>>(counts, offsets);
    k_scatter<<<NPAIR / 256, 256, 0, stream>>>(tk_e, offsets, fill, pair_token, slot_of);
    k_gemm1<<<dim3(TWO_D / BN, T_TOK / BM, E_NUM), 256, 0, stream>>>(xb, wgu, bgu, offsets, pair_token, gu);
    k_act<<<(NPAIR * 512) / 256, 256, 0, stream>>>(gu, gated);
    k_gemm2<<<dim3(H_DIM / BN, T_TOK / BM, E_NUM), 256, 0, stream>>>(gated, wd, bd, offsets, pairout);
    k_combine<<<T_TOK, 256, 0, stream>>>(pairout, slot_of, tk_w, y);
}